// Round 6
// baseline (322.078 us; speedup 1.0000x reference)
//
#include <hip/hip_runtime.h>

// Problem constants
#define T_ 64
#define P_ 144          // 12*12 windows per frame
#define NPAIR 9216      // T_*P_
#define C_ 1024
#define MID_ 256

#define MPF 16          // pairs per fused block -> 576 blocks
#define QST 264         // q_s bf16 row stride (264*2B: +4-bank row skew)
#define PSTW 1032       // pool_s bf16 row stride
#define USTW 1036       // u_s fp32 row stride

typedef __attribute__((ext_vector_type(4))) float f32x4;
typedef __attribute__((ext_vector_type(8))) __bf16 bf16x8;
typedef __attribute__((ext_vector_type(4))) __bf16 bf16x4;

__device__ __forceinline__ void async_copy16(const void* g, void* l) {
  __builtin_amdgcn_global_load_lds(
      (const __attribute__((address_space(1))) unsigned int*)g,
      (__attribute__((address_space(3))) unsigned int*)l, 16, 0, 0);
}

// ---------------------------------------------------------------------------
// prep: blocks [0,64): Wq [1024][256] -> Wqt bf16 [256][1024] (transpose+cast)
//       blocks [64,96): Wk [1024][256] -> Wkb bf16 (cast only, layout kept)
__global__ __launch_bounds__(256) void prep_kernel(
    const float* __restrict__ Wq, const float* __restrict__ Wk,
    __bf16* __restrict__ Wqt, __bf16* __restrict__ Wkb) {
  const int bid = blockIdx.x;
  const int tid = threadIdx.x;
  if (bid < 64) {
    // transpose one 128c x 32d tile of Wq into Wqt
    const int ct = bid >> 3, dt = bid & 7;
    __shared__ float tile[128][33];
    const int r = tid >> 3;             // 0..31
    const int c4 = (tid & 7) * 4;       // 0..28
#pragma unroll
    for (int s = 0; s < 4; ++s) {
      const int row = r + s * 32;       // c within tile
      const f32x4 v =
          *(const f32x4*)(Wq + (size_t)(ct * 128 + row) * MID_ + dt * 32 + c4);
      tile[row][c4 + 0] = v[0]; tile[row][c4 + 1] = v[1];
      tile[row][c4 + 2] = v[2]; tile[row][c4 + 3] = v[3];
    }
    __syncthreads();
    const int dd = tid >> 5;            // 0..7
    const int cc4 = (tid & 31) * 4;     // 0..124
#pragma unroll
    for (int s = 0; s < 4; ++s) {
      const int d = dd + s * 8;
      bf16x4 o;
#pragma unroll
      for (int j = 0; j < 4; ++j) o[j] = (__bf16)tile[cc4 + j][d];
      *(bf16x4*)(Wqt + (size_t)(dt * 32 + d) * C_ + ct * 128 + cc4) = o;
    }
  } else {
    const int b = bid - 64;
    const float* src = Wk + (size_t)b * 8192;
    __bf16* dst = Wkb + (size_t)b * 8192;
#pragma unroll
    for (int s = 0; s < 8; ++s) {
      const f32x4 v = *(const f32x4*)(src + tid * 4 + s * 1024);
      bf16x4 o;
#pragma unroll
      for (int j = 0; j < 4; ++j) o[j] = (__bf16)v[j];
      *(bf16x4*)(dst + tid * 4 + s * 1024) = o;
    }
  }
}

// ---------------------------------------------------------------------------
// fused: 576 blocks x 256 threads (4 waves), 16 pairs/block, LDS 74 KB
//        -> 2 blocks/CU co-resident (the m97 overlap regime).
//   A: pool 16 pairs -> bf16 LDS [16][PSTW]; stage bq
//   B: q = pooled @ Wqt^T + bq (M=16,N=256,K=1024; 16 KB Wqt slab/step via
//      global_load_lds w16, 2-barrier steps) -> q_s bf16 [16][QST]
//   C: u = q_s @ Wkb^T (M=16,N=1024,K=256; 64 KB Wkb slab/step, 8 steps;
//      u in regs: 16 f32x4/thread) -> u_s fp32 [16][USTW]
//   D: logits u.v_w (v re-read, L2-warm), softmax, out = pooled + sum a_w v_w
__global__ __launch_bounds__(256, 2) void fused_kernel(
    const __bf16* __restrict__ Wqt, const __bf16* __restrict__ Wkb,
    const float* __restrict__ bq, const float* __restrict__ img,
    float* __restrict__ out) {
  // LDS union layout (bytes):
  //   [0,1024)        bqs fp32
  //   [1024,9472)     q_s bf16 [16][QST]          (written B-end, read C)
  //   [9472,25856)    slabB 16KB   |  slabC 64KB at [9472,75008)
  //   [25856,58880)   pool_s bf16 [16][PSTW]      (A->B only)
  //   [9472,75776)    u_s fp32 [16][USTW]         (C-end -> D)
  __shared__ __align__(16) char lds[75776];
  float* bqs = (float*)lds;
  __bf16* q_s = (__bf16*)(lds + 1024);
  char* slab = lds + 9472;
  __bf16* pool_s = (__bf16*)(lds + 25856);
  float* u_s = (float*)(lds + 9472);

  const int tid = threadIdx.x;
  const int bid = blockIdx.x;
  const int lane = tid & 63;
  const int wv = tid >> 6;              // 0..3
  const int quad = lane >> 4, lr = lane & 15;

  // ---- Phase A: pool 16 pairs -> LDS bf16; stage bq ------------------------
  bqs[tid] = bq[tid];
#pragma unroll
  for (int s = 0; s < MPF; ++s) {
    const int gp = bid * MPF + s;
    const int t = gp / P_;
    const int pp = gp - t * P_;
    const int wy = pp / 12, wx = pp - wy * 12;
    const float* base = img + ((size_t)t * 576 + 48 * wy + 2 * wx) * C_;
    const int c = tid * 4;
    f32x4 sm = *(const f32x4*)(base + c);
    sm += *(const f32x4*)(base + C_ + c);
    sm += *(const f32x4*)(base + 24 * C_ + c);
    sm += *(const f32x4*)(base + 25 * C_ + c);
    sm *= 0.25f;
    bf16x4 pv;
#pragma unroll
    for (int q = 0; q < 4; ++q) pv[q] = (__bf16)sm[q];
    *(bf16x4*)(pool_s + s * PSTW + c) = pv;
  }

  // ---- Phase B: q = pooled @ Wqt^T + bq  (K=1024, 32 steps) ----------------
  f32x4 qacc[4] = {};
  const __bf16* gq = Wqt + (size_t)(tid >> 2) * C_ + (tid & 3) * 8;
  char* sdst = slab + tid * 16;
  for (int it = 0; it < 32; ++it) {
    const __bf16* src = gq + it * 32;
#pragma unroll
    for (int i = 0; i < 4; ++i)
      async_copy16(src + (size_t)i * 64 * C_, sdst + i * 4096);
    __syncthreads();   // slab landed (+ phase A pool writes on it=0)
    const bf16x8 a = *(const bf16x8*)(pool_s + lr * PSTW + it * 32 + quad * 8);
#pragma unroll
    for (int j = 0; j < 4; ++j) {
      const bf16x8 b =
          *(const bf16x8*)((__bf16*)slab + (wv * 64 + j * 16 + lr) * 32 + quad * 8);
      qacc[j] = __builtin_amdgcn_mfma_f32_16x16x32_bf16(a, b, qacc[j], 0, 0, 0);
    }
    __syncthreads();   // slab reads done before next overwrite
  }
  // q -> q_s bf16 (+bq). C/D frag map: col=lane&15(+j*16+wv*64), row=quad*4+r
#pragma unroll
  for (int j = 0; j < 4; ++j) {
    const int col = wv * 64 + j * 16 + lr;
    const float bv = bqs[col];
#pragma unroll
    for (int r = 0; r < 4; ++r)
      q_s[(quad * 4 + r) * QST + col] = (__bf16)(qacc[j][r] + bv);
  }

  // ---- Phase C: u = q_s @ Wkb^T  (K=256, 8 steps, u in regs) ---------------
  f32x4 uacc[16] = {};
  const __bf16* gk = Wkb + (size_t)(tid >> 2) * MID_ + (tid & 3) * 8;
  for (int it = 0; it < 8; ++it) {
    const __bf16* src = gk + it * 32;
#pragma unroll
    for (int i = 0; i < 16; ++i)
      async_copy16(src + (size_t)i * 64 * MID_, sdst + i * 4096);
    __syncthreads();   // slab landed (+ q_s writes on it=0)
    const bf16x8 aq = *(const bf16x8*)(q_s + lr * QST + it * 32 + quad * 8);
#pragma unroll
    for (int j = 0; j < 16; ++j) {
      const bf16x8 b =
          *(const bf16x8*)((__bf16*)slab + (wv * 256 + j * 16 + lr) * 32 + quad * 8);
      uacc[j] = __builtin_amdgcn_mfma_f32_16x16x32_bf16(aq, b, uacc[j], 0, 0, 0);
    }
    __syncthreads();   // slab + q_s reads done
  }
  // u -> u_s fp32 (overwrites q_s/slab region; reads drained by last sync)
#pragma unroll
  for (int j = 0; j < 16; ++j) {
    const int col = wv * 256 + j * 16 + lr;
#pragma unroll
    for (int r = 0; r < 4; ++r)
      u_s[(quad * 4 + r) * USTW + col] = uacc[j][r];
  }
  __syncthreads();

  // ---- Phase D: logits + softmax + output (16 lanes per pair) --------------
  const int p = tid >> 4;               // 0..15
  const int ln = tid & 15;
  const int gp = bid * MPF + p;
  const int t = gp / P_;
  const int pp = gp - t * P_;
  const int wy = pp / 12, wx = pp - wy * 12;
  const float* base = img + ((size_t)t * 576 + 48 * wy + 2 * wx) * C_;

  float pd0 = 0.f, pd1 = 0.f, pd2 = 0.f, pd3 = 0.f;
  for (int ch = 0; ch < 16; ++ch) {
    const int c = ln * 4 + ch * 64;
    const f32x4 u4 = *(const f32x4*)(u_s + p * USTW + c);
    const f32x4 v0 = *(const f32x4*)(base + c);
    const f32x4 v1 = *(const f32x4*)(base + C_ + c);
    const f32x4 v2 = *(const f32x4*)(base + 24 * C_ + c);
    const f32x4 v3 = *(const f32x4*)(base + 25 * C_ + c);
#pragma unroll
    for (int q = 0; q < 4; ++q) {
      pd0 += u4[q] * v0[q];
      pd1 += u4[q] * v1[q];
      pd2 += u4[q] * v2[q];
      pd3 += u4[q] * v3[q];
    }
  }
#pragma unroll
  for (int m = 8; m >= 1; m >>= 1) {   // reduce within 16-lane group
    pd0 += __shfl_xor(pd0, m);
    pd1 += __shfl_xor(pd1, m);
    pd2 += __shfl_xor(pd2, m);
    pd3 += __shfl_xor(pd3, m);
  }
  const float l0 = pd0 * 0.0625f, l1 = pd1 * 0.0625f;
  const float l2 = pd2 * 0.0625f, l3 = pd3 * 0.0625f;
  const float mx = fmaxf(fmaxf(l0, l1), fmaxf(l2, l3));
  const float e0 = __expf(l0 - mx), e1 = __expf(l1 - mx);
  const float e2 = __expf(l2 - mx), e3 = __expf(l3 - mx);
  const float inv = 1.f / (e0 + e1 + e2 + e3);
  const float a0 = e0 * inv + 0.25f, a1 = e1 * inv + 0.25f;
  const float a2 = e2 * inv + 0.25f, a3 = e3 * inv + 0.25f;
  float* op = out + (size_t)gp * C_;
  for (int ch = 0; ch < 16; ++ch) {
    const int c = ln * 4 + ch * 64;
    const f32x4 v0 = *(const f32x4*)(base + c);
    const f32x4 v1 = *(const f32x4*)(base + C_ + c);
    const f32x4 v2 = *(const f32x4*)(base + 24 * C_ + c);
    const f32x4 v3 = *(const f32x4*)(base + 25 * C_ + c);
    f32x4 o = a0 * v0 + a1 * v1 + a2 * v2 + a3 * v3;
    *(f32x4*)(op + c) = o;
  }
}

// ---------------------------------------------------------------------------
extern "C" void kernel_launch(void* const* d_in, const int* in_sizes, int n_in,
                              void* d_out, int out_size, void* d_ws,
                              size_t ws_size, hipStream_t stream) {
  const float* img = (const float*)d_in[0];
  const float* Wq = (const float*)d_in[1];
  const float* bq = (const float*)d_in[2];
  const float* Wk = (const float*)d_in[3];
  const float* bk = (const float*)d_in[4];  // constant under softmax -> unused
  (void)bk;
  float* out = (float*)d_out;

  // workspace (~1 MB): weights only
  char* ws = (char*)d_ws;
  __bf16* Wqt = (__bf16*)ws;                 // 256*1024*2 = 524,288
  __bf16* Wkb = (__bf16*)(ws + 524288);      // 1024*256*2 = 524,288

  // 1) weights: Wq -> Wqt (bf16 transpose), Wk -> Wkb (bf16 cast)
  prep_kernel<<<96, 256, 0, stream>>>(Wq, Wk, Wqt, Wkb);
  // 2) fully fused: pool -> q -> u -> softmax -> out (img read once from HBM)
  fused_kernel<<<NPAIR / MPF, 256, 0, stream>>>(Wqt, Wkb, bq, img, out);
}

// Round 7
// 285.370 us; speedup vs baseline: 1.1286x; 1.1286x over previous
//
#include <hip/hip_runtime.h>

// Problem constants
#define T_ 64
#define P_ 144          // 12*12 windows per frame
#define NPAIR 9216      // T_*P_
#define C_ 1024
#define MID_ 256

typedef __attribute__((ext_vector_type(4))) float f32x4;
typedef __attribute__((ext_vector_type(8))) __bf16 bf16x8;
typedef __attribute__((ext_vector_type(4))) __bf16 bf16x4;

__device__ __forceinline__ void async_copy16(const void* g, void* l) {
  __builtin_amdgcn_global_load_lds(
      (const __attribute__((address_space(1))) unsigned int*)g,
      (__attribute__((address_space(3))) unsigned int*)l, 16, 0, 0);
}

// ---------------------------------------------------------------------------
// K1: blocks [0, NPAIR): mean-pool 2x2 windows -> pooled bf16
//     blocks [NPAIR, +64): Wq [1024][256] -> Wqt bf16 [256][1024] (transpose)
//     blocks [NPAIR+64, +32): Wk [1024][256] -> Wkb bf16 (cast only)
__global__ __launch_bounds__(256) void pool_prep_kernel(
    const float* __restrict__ img, const float* __restrict__ Wq,
    const float* __restrict__ Wk, __bf16* __restrict__ poolb,
    __bf16* __restrict__ Wqt, __bf16* __restrict__ Wkb) {
  const int bid = blockIdx.x;
  const int tid = threadIdx.x;
  if (bid < NPAIR) {
    const int t = bid / P_;
    const int p = bid - t * P_;
    const int wy = p / 12, wx = p - wy * 12;
    const int c = tid * 4;
    const float* base = img + ((size_t)t * 576 + 48 * wy + 2 * wx) * C_;
    f32x4 s = *(const f32x4*)(base + c);
    s += *(const f32x4*)(base + (size_t)1 * C_ + c);
    s += *(const f32x4*)(base + (size_t)24 * C_ + c);
    s += *(const f32x4*)(base + (size_t)25 * C_ + c);
    s *= 0.25f;
    bf16x4 pv;
#pragma unroll
    for (int j = 0; j < 4; ++j) pv[j] = (__bf16)s[j];
    *(bf16x4*)(poolb + (size_t)bid * C_ + c) = pv;
  } else if (bid < NPAIR + 64) {
    // transpose one 128c x 32d tile of Wq into Wqt
    const int b = bid - NPAIR;
    const int ct = b >> 3, dt = b & 7;
    __shared__ float tile[128][33];
    const int r = tid >> 3;             // 0..31
    const int c4 = (tid & 7) * 4;       // 0..28
#pragma unroll
    for (int s = 0; s < 4; ++s) {
      const int row = r + s * 32;       // c within tile
      const f32x4 v =
          *(const f32x4*)(Wq + (size_t)(ct * 128 + row) * MID_ + dt * 32 + c4);
      tile[row][c4 + 0] = v[0]; tile[row][c4 + 1] = v[1];
      tile[row][c4 + 2] = v[2]; tile[row][c4 + 3] = v[3];
    }
    __syncthreads();
    const int dd = tid >> 5;            // 0..7
    const int cc4 = (tid & 31) * 4;     // 0..124
#pragma unroll
    for (int s = 0; s < 4; ++s) {
      const int d = dd + s * 8;
      bf16x4 o;
#pragma unroll
      for (int j = 0; j < 4; ++j) o[j] = (__bf16)tile[cc4 + j][d];
      *(bf16x4*)(Wqt + (size_t)(dt * 32 + d) * C_ + ct * 128 + cc4) = o;
    }
  } else {
    // cast Wk -> bf16, layout preserved ([c][d] == B^T layout for GEMM2)
    const int b = bid - NPAIR - 64;
    const float* src = Wk + (size_t)b * 8192;
    __bf16* dst = Wkb + (size_t)b * 8192;
#pragma unroll
    for (int s = 0; s < 8; ++s) {
      const f32x4 v = *(const f32x4*)(src + tid * 4 + s * 1024);
      bf16x4 o;
#pragma unroll
      for (int j = 0; j < 4; ++j) o[j] = (__bf16)v[j];
      *(bf16x4*)(dst + tid * 4 + s * 1024) = o;
    }
  }
}

// ---------------------------------------------------------------------------
// K2: q = pooled @ Wqt^T + bq   (9216x256, K=1024) -> bf16
// 64x128 tile (full-CU grid: 144 mt x 2 nt = 288 blocks), BK=32,
// global_load_lds w16, 2-barrier K-steps, 4 waves 2x2 (each 32x64).
__global__ __launch_bounds__(256) void gemm_q_kernel(
    const __bf16* __restrict__ A, const __bf16* __restrict__ Bt,
    const float* __restrict__ bias, __bf16* __restrict__ Q) {
  __shared__ __align__(16) __bf16 As[64 * 32];
  __shared__ __align__(16) __bf16 Bs[128 * 32];
  const int bid = blockIdx.x;
  const int mt = bid >> 1, nt = bid & 1;
  const int tid = threadIdx.x;
  const int lane = tid & 63;
  const int wv = tid >> 6;
  const int quad = lane >> 4, lr = lane & 15;
  const int wm = wv >> 1, wn = wv & 1;

  const int r0 = tid >> 2, p0 = tid & 3;
  const int wvb = (tid & ~63) * 16;
  const __bf16* ga0 = A + ((size_t)mt * 64 + r0) * (size_t)C_ + p0 * 8;
  const __bf16* gb0 = Bt + ((size_t)nt * 128 + r0) * (size_t)C_ + p0 * 8;
  const __bf16* gb1 = gb0 + (size_t)64 * C_;
  char* AsB0 = (char*)As + wvb;
  char* BsB0 = (char*)Bs + wvb;
  char* BsB1 = (char*)Bs + 4096 + wvb;

  f32x4 acc[2][4] = {};

  for (int it = 0; it < 32; ++it) {
    async_copy16(ga0, AsB0);
    async_copy16(gb0, BsB0);
    async_copy16(gb1, BsB1);
    ga0 += 32; gb0 += 32; gb1 += 32;
    __syncthreads();
    bf16x8 a[2], b[4];
    const bf16x8* Ap = (const bf16x8*)As;
    const bf16x8* Bp = (const bf16x8*)Bs;
#pragma unroll
    for (int i = 0; i < 2; ++i) a[i] = Ap[(wm * 32 + i * 16 + lr) * 4 + quad];
#pragma unroll
    for (int i = 0; i < 4; ++i) b[i] = Bp[(wn * 64 + i * 16 + lr) * 4 + quad];
#pragma unroll
    for (int mi = 0; mi < 2; ++mi)
#pragma unroll
      for (int ni = 0; ni < 4; ++ni)
        acc[mi][ni] = __builtin_amdgcn_mfma_f32_16x16x32_bf16(
            a[mi], b[ni], acc[mi][ni], 0, 0, 0);
    __syncthreads();
  }

  const int colb = nt * 128 + wn * 64;
  const int rowb = mt * 64 + wm * 32 + quad * 4;
#pragma unroll
  for (int ni = 0; ni < 4; ++ni) {
    const int col = colb + ni * 16 + lr;
    const float bv = bias[col];
#pragma unroll
    for (int mi = 0; mi < 2; ++mi) {
      const int row = rowb + mi * 16;
#pragma unroll
      for (int r = 0; r < 4; ++r)
        Q[(size_t)(row + r) * MID_ + col] = (__bf16)(acc[mi][ni][r] + bv);
    }
  }
}

// ---------------------------------------------------------------------------
// K3: u = q @ Wkb^T   (9216x1024, K=256) -> bf16. grid 72x8 = 576 blocks.
__global__ __launch_bounds__(256) void gemm_u_kernel(
    const __bf16* __restrict__ A, const __bf16* __restrict__ Bt,
    __bf16* __restrict__ U) {
  __shared__ __align__(16) __bf16 As[128 * 32];
  __shared__ __align__(16) __bf16 Bs[128 * 32];
  const int bid = blockIdx.x;
  const int mt = bid >> 3, nt = bid & 7;
  const int tid = threadIdx.x;
  const int lane = tid & 63;
  const int wv = tid >> 6;
  const int quad = lane >> 4, lr = lane & 15;
  const int wm = wv >> 1, wn = wv & 1;

  const int r0 = tid >> 2, p0 = tid & 3;
  const int wvb = (tid & ~63) * 16;
  const __bf16* ga0 = A + ((size_t)mt * 128 + r0) * (size_t)MID_ + p0 * 8;
  const __bf16* ga1 = ga0 + (size_t)64 * MID_;
  const __bf16* gb0 = Bt + ((size_t)nt * 128 + r0) * (size_t)MID_ + p0 * 8;
  const __bf16* gb1 = gb0 + (size_t)64 * MID_;
  char* AsB0 = (char*)As + wvb;
  char* AsB1 = (char*)As + 4096 + wvb;
  char* BsB0 = (char*)Bs + wvb;
  char* BsB1 = (char*)Bs + 4096 + wvb;

  f32x4 acc[4][4] = {};

  for (int it = 0; it < 8; ++it) {
    async_copy16(ga0, AsB0);
    async_copy16(ga1, AsB1);
    async_copy16(gb0, BsB0);
    async_copy16(gb1, BsB1);
    ga0 += 32; ga1 += 32; gb0 += 32; gb1 += 32;
    __syncthreads();
    bf16x8 a[4], b[4];
    const bf16x8* Ap = (const bf16x8*)As;
    const bf16x8* Bp = (const bf16x8*)Bs;
#pragma unroll
    for (int i = 0; i < 4; ++i) {
      a[i] = Ap[(wm * 64 + i * 16 + lr) * 4 + quad];
      b[i] = Bp[(wn * 64 + i * 16 + lr) * 4 + quad];
    }
#pragma unroll
    for (int mi = 0; mi < 4; ++mi)
#pragma unroll
      for (int ni = 0; ni < 4; ++ni)
        acc[mi][ni] = __builtin_amdgcn_mfma_f32_16x16x32_bf16(
            a[mi], b[ni], acc[mi][ni], 0, 0, 0);
    __syncthreads();
  }

  const int colb = nt * 128 + wn * 64;
  const int rowb = mt * 128 + wm * 64 + quad * 4;
#pragma unroll
  for (int ni = 0; ni < 4; ++ni) {
    const int col = colb + ni * 16 + lr;
#pragma unroll
    for (int mi = 0; mi < 4; ++mi) {
      const int row = rowb + mi * 16;
#pragma unroll
      for (int r = 0; r < 4; ++r)
        U[(size_t)(row + r) * C_ + col] = (__bf16)acc[mi][ni][r];
    }
  }
}

// ---------------------------------------------------------------------------
// K4: one PAIR per WAVE (4 pairs/block, 2304 blocks): no barriers, no LDS.
// logit_w = (u·v_w)*scale via 64-lane butterfly; out = sum (a_w+0.25) v_w.
__global__ __launch_bounds__(256) void attn_out_kernel(
    const __bf16* __restrict__ U, const float* __restrict__ img,
    float* __restrict__ out) {
  const int tid = threadIdx.x;
  const int wv = tid >> 6, lane = tid & 63;
  const int pair = blockIdx.x * 4 + wv;
  const int t = pair / P_;
  const int pp = pair - t * P_;
  const int wy = pp / 12, wx = pp - wy * 12;
  const float* base = img + ((size_t)t * 576 + 48 * wy + 2 * wx) * C_;

  f32x4 v0[4], v1[4], v2[4], v3[4], u4[4];
  float pd0 = 0.f, pd1 = 0.f, pd2 = 0.f, pd3 = 0.f;
#pragma unroll
  for (int ch = 0; ch < 4; ++ch) {
    const int c = lane * 4 + ch * 256;
    v0[ch] = *(const f32x4*)(base + c);
    v1[ch] = *(const f32x4*)(base + (size_t)1 * C_ + c);
    v2[ch] = *(const f32x4*)(base + (size_t)24 * C_ + c);
    v3[ch] = *(const f32x4*)(base + (size_t)25 * C_ + c);
    const bf16x4 ub = *(const bf16x4*)(U + (size_t)pair * C_ + c);
#pragma unroll
    for (int j = 0; j < 4; ++j) u4[ch][j] = (float)ub[j];
#pragma unroll
    for (int j = 0; j < 4; ++j) {
      pd0 += u4[ch][j] * v0[ch][j];
      pd1 += u4[ch][j] * v1[ch][j];
      pd2 += u4[ch][j] * v2[ch][j];
      pd3 += u4[ch][j] * v3[ch][j];
    }
  }
#pragma unroll
  for (int m = 32; m >= 1; m >>= 1) {
    pd0 += __shfl_xor(pd0, m);
    pd1 += __shfl_xor(pd1, m);
    pd2 += __shfl_xor(pd2, m);
    pd3 += __shfl_xor(pd3, m);
  }
  const float l0 = pd0 * 0.0625f, l1 = pd1 * 0.0625f;
  const float l2 = pd2 * 0.0625f, l3 = pd3 * 0.0625f;
  const float mx = fmaxf(fmaxf(l0, l1), fmaxf(l2, l3));
  const float e0 = __expf(l0 - mx), e1 = __expf(l1 - mx);
  const float e2 = __expf(l2 - mx), e3 = __expf(l3 - mx);
  const float inv = 1.f / (e0 + e1 + e2 + e3);
  const float a0 = e0 * inv + 0.25f, a1 = e1 * inv + 0.25f;
  const float a2 = e2 * inv + 0.25f, a3 = e3 * inv + 0.25f;
  float* op = out + (size_t)pair * C_;
#pragma unroll
  for (int ch = 0; ch < 4; ++ch) {
    const int c = lane * 4 + ch * 256;
    f32x4 o = a0 * v0[ch] + a1 * v1[ch] + a2 * v2[ch] + a3 * v3[ch];
    *(f32x4*)(op + c) = o;
  }
}

// ---------------------------------------------------------------------------
extern "C" void kernel_launch(void* const* d_in, const int* in_sizes, int n_in,
                              void* d_out, int out_size, void* d_ws,
                              size_t ws_size, hipStream_t stream) {
  const float* img = (const float*)d_in[0];
  const float* Wq = (const float*)d_in[1];
  const float* bq = (const float*)d_in[2];
  const float* Wk = (const float*)d_in[3];
  const float* bk = (const float*)d_in[4];  // constant under softmax -> unused
  (void)bk;
  float* out = (float*)d_out;

  // workspace layout (~43.5 MB)
  char* ws = (char*)d_ws;
  __bf16* poolb = (__bf16*)ws;               //  9216*1024*2 = 18,874,368
  __bf16* Wqt = (__bf16*)(ws + 18874368);    //   256*1024*2 =    524,288
  __bf16* Wkb = (__bf16*)(ws + 19398656);    //  1024*256*2  =    524,288
  __bf16* Qb  = (__bf16*)(ws + 19922944);    //  9216*256*2  =  4,718,592
  __bf16* U   = (__bf16*)(ws + 24641536);    //  9216*1024*2 = 18,874,368

  // 1) pool -> bf16; Wq transpose->bf16; Wk cast->bf16 (one launch)
  pool_prep_kernel<<<NPAIR + 96, 256, 0, stream>>>(img, Wq, Wk, poolb, Wqt, Wkb);
  // 2) q = pooled @ Wq + bq   (64x128 tiles -> 288 blocks, full CU coverage)
  gemm_q_kernel<<<288, 256, 0, stream>>>(poolb, Wqt, bq, Qb);
  // 3) u = q @ Wk^T           (q·bk drops under softmax)
  gemm_u_kernel<<<576, 256, 0, stream>>>(Qb, Wkb, U);
  // 4) logits, softmax, weighted output (1 pair/wave, no barriers)
  attn_out_kernel<<<NPAIR / 4, 256, 0, stream>>>(U, img, out);
}